// Round 4
// baseline (4955.730 us; speedup 1.0000x reference)
//
#include <hip/hip_runtime.h>
#include <hip/hip_fp16.h>
#include <cstdint>
#include <cstddef>

#define TT 512
#define BB 64
#define EE 256
#define HH 256
#define G4 1024   // 4*H
#define DD 512    // 2*H
#define NCLS 5
#define CH 64     // time-steps per chunk
#define NCH (TT / CH)

typedef _Float16 half8 __attribute__((ext_vector_type(8)));
typedef float f32x4 __attribute__((ext_vector_type(4)));

// Workspace layout (bytes). Total = 52,961,280 B (~50.5 MB, matches known-good).
#define OFF_XGF   0ull                 // 8,388,608  fp16 [CH][64][1024]
#define OFF_XGB   8388608ull           // 8,388,608
#define OFF_OUTB  16777216ull          // 33,554,432 fp16 [512][64][512]
#define OFF_WHHF  50331648ull          // 1,048,576  fp16 frag [2][16][4][8][64][8]
#define OFF_WIHF  51380224ull          // 1,048,576  fp16 frag [2][64][8][64][8]
#define OFF_BIAS  52428800ull          // 8,192      f32 [2][1024]
#define OFF_HST   52436992ull          // 131,072    f32 [2][64][256]
#define OFF_CST   52568064ull          // 131,072
#define OFF_LOG   52699136ull          // 131,072    f32 [512][64]
#define OFF_ATT   52830208ull          // 131,072

__device__ __forceinline__ f32x4 mfma16(half8 a, half8 b, f32x4 c) {
  return __builtin_amdgcn_mfma_f32_16x16x32_f16(a, b, c, 0, 0, 0);
}
__device__ __forceinline__ float sigm(float x) {
  return __fdividef(1.f, 1.f + __expf(-x));
}
__device__ __forceinline__ float tanh_(float x) {
  float e = __expf(2.f * x);
  return 1.f - __fdividef(2.f, e + 1.f);
}

// ---------------------------------------------------------------------------
// Fragment-order the weights (fp16).
// Whhfrag[d][w][q][ks][lane][r] = Whh_d[q*256 + w*16 + (lane&15)][ks*32 + (lane>>4)*8 + r]
// Wihfrag[d][g16][ks][lane][r]  = Wih_d[g16*16 + (lane&15)][ks*32 + (lane>>4)*8 + r]
// ---------------------------------------------------------------------------
__global__ __launch_bounds__(256) void make_frags(
    const float* __restrict__ WhhF, const float* __restrict__ WhhB,
    const float* __restrict__ WihF, const float* __restrict__ WihB,
    __half* __restrict__ whhfrag, __half* __restrict__ wihfrag)
{
  int idx = blockIdx.x * 256 + threadIdx.x;   // 0 .. 2^20-1
  int r = idx & 7, lane = (idx >> 3) & 63, ks = (idx >> 9) & 7;
  int k = ks * 32 + (lane >> 4) * 8 + r;
  if (idx < (1 << 19)) {
    int q = (idx >> 12) & 3, w = (idx >> 14) & 15, d = (idx >> 18) & 1;
    const float* W = d ? WhhB : WhhF;
    int g = q * 256 + w * 16 + (lane & 15);
    whhfrag[idx] = __float2half(W[(size_t)g * HH + k]);
  } else {
    int e = idx - (1 << 19);
    int g16 = (e >> 12) & 63, d = (e >> 18) & 1;
    const float* W = d ? WihB : WihF;
    int g = g16 * 16 + (lane & 15);
    wihfrag[e] = __float2half(W[(size_t)g * EE + k]);
  }
}

__global__ __launch_bounds__(256) void bias_prep(
    const float* __restrict__ bihF, const float* __restrict__ bhhF,
    const float* __restrict__ bihB, const float* __restrict__ bhhB,
    float* __restrict__ bias)
{
  int i = blockIdx.x * 256 + threadIdx.x;    // 0..2047
  int d = i >> 10, g = i & 1023;
  bias[i] = (d ? bihB : bihF)[g] + (d ? bhhB : bhhF)[g];
}

// ---------------------------------------------------------------------------
// xg chunk via MFMA: xg[ls][b][g] = x[b]·Wih[g] + bias[g]  (fp16 in, f32 acc,
// fp16 out). Block: one t-step (64 batch rows) x 64 gate cols, 4 waves.
// ---------------------------------------------------------------------------
__global__ __launch_bounds__(256) void xg_mfma(
    int c, const int* __restrict__ embed, const float* __restrict__ emb,
    const __half* __restrict__ wihfrag, const float* __restrict__ biassum,
    __half* __restrict__ xgF, __half* __restrict__ xgB)
{
  const int d = blockIdx.z, ls = blockIdx.x, gblk = blockIdx.y;
  int t = c * CH + ls;
  if (d) t = TT - 1 - t;
  __half* xg = d ? xgB : xgF;
  const int tid = threadIdx.x, w = tid >> 6, l = tid & 63;

  __shared__ int idx[64];
  __shared__ unsigned short xs[64 * 256];   // 32 KB, swizzled fp16 x

  if (tid < 64) idx[tid] = embed[t * BB + tid];
  __syncthreads();

  // stage x: thread owns row rr, 64-col quarter cq
  {
    const int rr = tid >> 2, cq = (tid & 3) * 64;
    const float* src = emb + (size_t)idx[rr] * EE + cq;
#pragma unroll
    for (int j = 0; j < 8; ++j) {
      float4 a = *(const float4*)(src + j * 8);
      float4 b = *(const float4*)(src + j * 8 + 4);
      half8 hv;
      hv[0] = (_Float16)a.x; hv[1] = (_Float16)a.y; hv[2] = (_Float16)a.z; hv[3] = (_Float16)a.w;
      hv[4] = (_Float16)b.x; hv[5] = (_Float16)b.y; hv[6] = (_Float16)b.z; hv[7] = (_Float16)b.w;
      int hidx = (rr * 256 + cq + j * 8) ^ ((rr & 7) << 3);
      *(half8*)&xs[hidx] = hv;
    }
  }
  __syncthreads();

  // B fragments (L2-resident, frag-ordered)
  const __half* bfb = wihfrag + (size_t)((d * 64 + gblk * 4) * 8) * 512 + l * 8;
  half8 Bf[4][8];
#pragma unroll
  for (int ct = 0; ct < 4; ++ct)
#pragma unroll
    for (int ks = 0; ks < 8; ++ks)
      Bf[ct][ks] = *(const half8*)(bfb + (ct * 8 + ks) * 512);

  f32x4 acc[4];
#pragma unroll
  for (int ct = 0; ct < 4; ++ct) {
    float bv = biassum[d * 1024 + gblk * 64 + ct * 16 + (l & 15)];
    acc[ct][0] = bv; acc[ct][1] = bv; acc[ct][2] = bv; acc[ct][3] = bv;
  }

  const int arow = w * 16 + (l & 15);
#pragma unroll
  for (int ks = 0; ks < 8; ++ks) {
    int hidx = (arow * 256 + ks * 32 + (l >> 4) * 8) ^ ((arow & 7) << 3);
    half8 af = *(const half8*)&xs[hidx];
#pragma unroll
    for (int ct = 0; ct < 4; ++ct)
      acc[ct] = mfma16(af, Bf[ct][ks], acc[ct]);
  }

#pragma unroll
  for (int ct = 0; ct < 4; ++ct)
#pragma unroll
    for (int r = 0; r < 4; ++r) {
      int b = w * 16 + (l >> 4) * 4 + r;
      int g = gblk * 64 + ct * 16 + (l & 15);
      xg[((size_t)ls * 64 + b) * G4 + g] = __float2half(acc[ct][r]);
    }
}

// ---------------------------------------------------------------------------
// LSTM scan chunk via MFMA, weight-STREAMING version. grid (4,2): 16 batch
// rows x dir per block, 16 waves; wave w owns units [16w,16w+16) for all 4
// gates. Whh frags are NOT register-resident (512KB/dir > VGPR file): they
// are re-read from L2 every step, 1:1 interleaved with the MFMAs. h fp16 in
// swizzled LDS double buffer; c f32 in regs.
// __launch_bounds__(1024, 4): force 1 block/CU -> 128-VGPR cap, no spill.
// ---------------------------------------------------------------------------
__global__ __launch_bounds__(1024, 4) void scan_mfma(
    int c, const __half* __restrict__ xgF, const __half* __restrict__ xgB,
    const __half* __restrict__ whhfrag,
    const float* __restrict__ hin, const float* __restrict__ cin,
    float* __restrict__ hstate, float* __restrict__ cstate,
    __half* __restrict__ outb)
{
  const int d = blockIdx.y, bx = blockIdx.x;
  const int tid = threadIdx.x, w = tid >> 6, l = tid & 63;
  const __half* xg = d ? xgB : xgF;

  __shared__ unsigned short hb[2][16 * 256];   // 2 x 8 KB, swizzled fp16 h

  // Per-wave weight-fragment base (stays in L2 across the whole scan)
  const __half* bfb = whhfrag + (size_t)((d * 16 + w) * 32) * 512 + l * 8;

  const int u = w * 16 + (l & 15);
  const int qr = l >> 4;
  float cst[4], hval[4];
#pragma unroll
  for (int r = 0; r < 4; ++r) {
    int br = qr * 4 + r;
    int gb = d * BB + bx * 16 + br;
    cst[r] = cin[(size_t)gb * HH + u];
    float hv = hin[(size_t)gb * HH + u];
    hval[r] = hv;
    hb[0][(br * 256 + u) ^ ((br & 7) << 3)] = __half_as_ushort(__float2half(hv));
  }
  __syncthreads();

  // xg base for this lane: rows (bx*16 + qr*4 + r), col q*256 + u
  const __half* xgbase = xg + (size_t)(bx * 16 + qr * 4) * G4 + u;

  int buf = 0;
  for (int ls = 0; ls < CH; ++ls) {
    int t = c * CH + ls;
    if (d) t = TT - 1 - t;

    // A fragments: h_prev (16 batch x 256 units) from LDS
    half8 af[8];
#pragma unroll
    for (int ks = 0; ks < 8; ++ks) {
      int hidx = ((l & 15) * 256 + ks * 32 + qr * 8) ^ (((l & 15) & 7) << 3);
      af[ks] = *(const half8*)&hb[buf][hidx];
    }

    // C-init from xg (already includes x@Wih^T + biases)
    f32x4 acc[4];
#pragma unroll
    for (int q = 0; q < 4; ++q)
#pragma unroll
      for (int r = 0; r < 4; ++r)
        acc[q][r] = __half2float(xgbase[(size_t)(ls * 64 + r) * G4 + q * 256]);

    // Stream B-frags from L2, 1:1 with MFMAs
#pragma unroll
    for (int ks = 0; ks < 8; ++ks) {
#pragma unroll
      for (int q = 0; q < 4; ++q) {
        half8 bf = *(const half8*)(bfb + (q * 8 + ks) * 512);
        acc[q] = mfma16(af[ks], bf, acc[q]);
      }
    }

#pragma unroll
    for (int r = 0; r < 4; ++r) {
      float ig = sigm(acc[0][r]);
      float fg = sigm(acc[1][r]);
      float gg = tanh_(acc[2][r]);
      float og = sigm(acc[3][r]);
      cst[r] = fg * cst[r] + ig * gg;
      float hv = og * tanh_(cst[r]);
      hval[r] = hv;
      int br = qr * 4 + r;
      unsigned short hu = __half_as_ushort(__float2half(hv));
      hb[buf ^ 1][(br * 256 + u) ^ ((br & 7) << 3)] = hu;
      outb[((size_t)t * BB + bx * 16 + br) * DD + d * HH + u] = __ushort_as_half(hu);
    }
    __syncthreads();
    buf ^= 1;
  }

#pragma unroll
  for (int r = 0; r < 4; ++r) {
    int gb = d * BB + bx * 16 + qr * 4 + r;
    hstate[(size_t)gb * HH + u] = hval[r];
    cstate[(size_t)gb * HH + u] = cst[r];
  }
}

// ---------------------------------------------------------------------------
// logits[r] = sum_e tanh( (out[r,:] @ W_word)[e] + b_word[e] ) * proj[e]
// ---------------------------------------------------------------------------
__global__ __launch_bounds__(1024, 1) void squish_logits(
    const __half* __restrict__ outb, const float* __restrict__ Ww,
    const float* __restrict__ bw, const float* __restrict__ proj,
    float* __restrict__ logits)
{
  const int r0 = blockIdx.x * 64;
  const int tid = threadIdx.x;
  const int tm = tid >> 6;        // 0..15
  const int tn = tid & 63;        // 0..63
  __shared__ float As[16][68];
  __shared__ float Bs[16][516];
  __shared__ float red[64][65];

  float acc[4][8] = {};
  const int am = tid >> 4, ak = tid & 15;
  const int bk = tid >> 7, bn = (tid & 127) * 4;

  for (int k0 = 0; k0 < DD; k0 += 16) {
    float a0 = __half2float(outb[(size_t)(r0 + am) * DD + k0 + ak]);
    float4 b0 = *(const float4*)&Ww[(size_t)(k0 + bk) * DD + bn];
    float4 b1 = *(const float4*)&Ww[(size_t)(k0 + bk + 8) * DD + bn];
    __syncthreads();
    As[ak][am] = a0;
    *(float4*)&Bs[bk][bn] = b0;
    *(float4*)&Bs[bk + 8][bn] = b1;
    __syncthreads();
#pragma unroll
    for (int k = 0; k < 16; ++k) {
      float4 a = *(const float4*)&As[k][tm * 4];
      float4 p0 = *(const float4*)&Bs[k][tn * 8];
      float4 p1 = *(const float4*)&Bs[k][tn * 8 + 4];
      float av[4] = {a.x, a.y, a.z, a.w};
#pragma unroll
      for (int i = 0; i < 4; ++i) {
        acc[i][0] += av[i] * p0.x; acc[i][1] += av[i] * p0.y;
        acc[i][2] += av[i] * p0.z; acc[i][3] += av[i] * p0.w;
        acc[i][4] += av[i] * p1.x; acc[i][5] += av[i] * p1.y;
        acc[i][6] += av[i] * p1.z; acc[i][7] += av[i] * p1.w;
      }
    }
  }
  float partial[4] = {0.f, 0.f, 0.f, 0.f};
#pragma unroll
  for (int jj = 0; jj < 8; ++jj) {
    int col = tn * 8 + jj;
    float bwv = bw[col], pv = proj[col];
#pragma unroll
    for (int i = 0; i < 4; ++i)
      partial[i] += tanhf(acc[i][jj] + bwv) * pv;
  }
#pragma unroll
  for (int i = 0; i < 4; ++i) red[tm * 4 + i][tn] = partial[i];
  __syncthreads();
  if (tid < 64) {
    float s = 0.f;
    for (int x = 0; x < 64; ++x) s += red[tid][x];
    logits[r0 + tid] = s;
  }
}

// ---------------------------------------------------------------------------
__global__ __launch_bounds__(256) void softmax_t(const float* __restrict__ logits,
                                                 float* __restrict__ attn)
{
  const int b = blockIdx.x;
  const int tid = threadIdx.x;
  __shared__ float sm[256];
  float v0 = logits[tid * BB + b];
  float v1 = logits[(tid + 256) * BB + b];
  sm[tid] = fmaxf(v0, v1);
  __syncthreads();
  for (int s = 128; s > 0; s >>= 1) {
    if (tid < s) sm[tid] = fmaxf(sm[tid], sm[tid + s]);
    __syncthreads();
  }
  float M = sm[0];
  __syncthreads();
  float e0 = expf(v0 - M), e1 = expf(v1 - M);
  sm[tid] = e0 + e1;
  __syncthreads();
  for (int s = 128; s > 0; s >>= 1) {
    if (tid < s) sm[tid] += sm[tid + s];
    __syncthreads();
  }
  float inv = 1.f / sm[0];
  attn[tid * BB + b] = e0 * inv;
  attn[(tid + 256) * BB + b] = e1 * inv;
}

// ---------------------------------------------------------------------------
__global__ __launch_bounds__(512) void vec_final(
    const __half* __restrict__ outb, const float* __restrict__ attn,
    const float* __restrict__ linW, const float* __restrict__ linb,
    float* __restrict__ y)
{
  const int b = blockIdx.x;
  const int d = threadIdx.x;
  float acc = 0.f;
  for (int t = 0; t < TT; ++t)
    acc += attn[t * BB + b] * __half2float(outb[((size_t)t * BB + b) * DD + d]);
  __shared__ float red[512];
  for (int cls = 0; cls < NCLS; ++cls) {
    red[d] = acc * linW[cls * DD + d];
    __syncthreads();
    for (int s = 256; s > 0; s >>= 1) {
      if (d < s) red[d] += red[d + s];
      __syncthreads();
    }
    if (d == 0) y[b * NCLS + cls] = red[0] + linb[cls];
    __syncthreads();
  }
}

// ---------------------------------------------------------------------------
extern "C" void kernel_launch(void* const* d_in, const int* in_sizes, int n_in,
                              void* d_out, int out_size, void* d_ws, size_t ws_size,
                              hipStream_t stream) {
  const int*   embed     = (const int*)d_in[0];
  const float* h0        = (const float*)d_in[1];
  const float* c0        = (const float*)d_in[2];
  const float* emb_table = (const float*)d_in[3];
  const float* Wih_f     = (const float*)d_in[4];
  const float* Whh_f     = (const float*)d_in[5];
  const float* bih_f     = (const float*)d_in[6];
  const float* bhh_f     = (const float*)d_in[7];
  const float* Wih_b     = (const float*)d_in[8];
  const float* Whh_b     = (const float*)d_in[9];
  const float* bih_b     = (const float*)d_in[10];
  const float* bhh_b     = (const float*)d_in[11];
  const float* W_word    = (const float*)d_in[12];
  const float* b_word    = (const float*)d_in[13];
  const float* proj_word = (const float*)d_in[14];
  const float* lin_W     = (const float*)d_in[15];
  const float* lin_b     = (const float*)d_in[16];

  char* ws = (char*)d_ws;
  __half* xgF     = (__half*)(ws + OFF_XGF);
  __half* xgB     = (__half*)(ws + OFF_XGB);
  __half* outb    = (__half*)(ws + OFF_OUTB);
  __half* whhfrag = (__half*)(ws + OFF_WHHF);
  __half* wihfrag = (__half*)(ws + OFF_WIHF);
  float*  biassum = (float*)(ws + OFF_BIAS);
  float*  hstate  = (float*)(ws + OFF_HST);
  float*  cstate  = (float*)(ws + OFF_CST);
  float*  logits  = (float*)(ws + OFF_LOG);
  float*  attn    = (float*)(ws + OFF_ATT);

  make_frags<<<4096, 256, 0, stream>>>(Whh_f, Whh_b, Wih_f, Wih_b, whhfrag, wihfrag);
  bias_prep<<<8, 256, 0, stream>>>(bih_f, bhh_f, bih_b, bhh_b, biassum);

  for (int c = 0; c < NCH; ++c) {
    xg_mfma<<<dim3(CH, 16, 2), 256, 0, stream>>>(c, embed, emb_table,
        wihfrag, biassum, xgF, xgB);
    const float* hin = (c == 0) ? h0 : hstate;
    const float* cin = (c == 0) ? c0 : cstate;
    scan_mfma<<<dim3(4, 2), 1024, 0, stream>>>(c, xgF, xgB, whhfrag,
        hin, cin, hstate, cstate, outb);
  }

  squish_logits<<<512, 1024, 0, stream>>>(outb, W_word, b_word, proj_word, logits);
  softmax_t<<<64, 256, 0, stream>>>(logits, attn);
  vec_final<<<64, 512, 0, stream>>>(outb, attn, lin_W, lin_b, (float*)d_out);
}

// Round 5
// 3766.856 us; speedup vs baseline: 1.3156x; 1.3156x over previous
//
#include <hip/hip_runtime.h>
#include <hip/hip_fp16.h>
#include <cstdint>
#include <cstddef>

#define TT 512
#define BB 64
#define EE 256
#define HH 256
#define G4 1024   // 4*H
#define DD 512    // 2*H
#define NCLS 5
#define CH 64     // time-steps per chunk
#define NCH (TT / CH)

typedef _Float16 half8 __attribute__((ext_vector_type(8)));
typedef float f32x4 __attribute__((ext_vector_type(4)));

// Workspace layout (bytes). Total = 52,961,280 B (~50.5 MB, known-good size).
#define OFF_XGF   0ull                 // 8,388,608  fp16 frag-ordered [CH*4][64][256]
#define OFF_XGB   8388608ull           // 8,388,608
#define OFF_OUTB  16777216ull          // 33,554,432 fp16 [512][64][512]
#define OFF_WHHF  50331648ull          // 1,048,576  fp16 frag [2][16][4][8][64][8]
#define OFF_WIHF  51380224ull          // 1,048,576  fp16 frag [2][64][8][64][8]
#define OFF_BIAS  52428800ull          // 8,192      f32 [2][1024]
#define OFF_HST   52436992ull          // 131,072    f32 [2][64][256]
#define OFF_CST   52568064ull          // 131,072
#define OFF_LOG   52699136ull          // 131,072    f32 [512][64]
#define OFF_ATT   52830208ull          // 131,072

__device__ __forceinline__ f32x4 mfma16(half8 a, half8 b, f32x4 c) {
  return __builtin_amdgcn_mfma_f32_16x16x32_f16(a, b, c, 0, 0, 0);
}
__device__ __forceinline__ float sigm(float x) {
  return __fdividef(1.f, 1.f + __expf(-x));
}
__device__ __forceinline__ float tanh_(float x) {
  float e = __expf(2.f * x);
  return 1.f - __fdividef(2.f, e + 1.f);
}

// h LDS swizzle: row br, unit u -> index
#define HSWZ(br, u) ((((br) * 256) + (u)) ^ (((br) & 7) << 3))

// ---------------------------------------------------------------------------
// Fragment-order the weights (fp16).  (unchanged, known-good)
// Whhfrag[d][wv][q][ks][lane][r] = Whh_d[q*256 + wv*16 + (lane&15)][ks*32 + (lane>>4)*8 + r]
// Wihfrag[d][g16][ks][lane][r]   = Wih_d[g16*16 + (lane&15)][ks*32 + (lane>>4)*8 + r]
// ---------------------------------------------------------------------------
__global__ __launch_bounds__(256) void make_frags(
    const float* __restrict__ WhhF, const float* __restrict__ WhhB,
    const float* __restrict__ WihF, const float* __restrict__ WihB,
    __half* __restrict__ whhfrag, __half* __restrict__ wihfrag)
{
  int idx = blockIdx.x * 256 + threadIdx.x;   // 0 .. 2^20-1
  int r = idx & 7, lane = (idx >> 3) & 63, ks = (idx >> 9) & 7;
  int k = ks * 32 + (lane >> 4) * 8 + r;
  if (idx < (1 << 19)) {
    int q = (idx >> 12) & 3, wv = (idx >> 14) & 15, d = (idx >> 18) & 1;
    const float* W = d ? WhhB : WhhF;
    int g = q * 256 + wv * 16 + (lane & 15);
    whhfrag[idx] = __float2half(W[(size_t)g * HH + k]);
  } else {
    int e = idx - (1 << 19);
    int g16 = (e >> 12) & 63, d = (e >> 18) & 1;
    const float* W = d ? WihB : WihF;
    int g = g16 * 16 + (lane & 15);
    wihfrag[e] = __float2half(W[(size_t)g * EE + k]);
  }
}

__global__ __launch_bounds__(256) void bias_prep(
    const float* __restrict__ bihF, const float* __restrict__ bhhF,
    const float* __restrict__ bihB, const float* __restrict__ bhhB,
    float* __restrict__ bias)
{
  int i = blockIdx.x * 256 + threadIdx.x;    // 0..2047
  int d = i >> 10, g = i & 1023;
  bias[i] = (d ? bihB : bihF)[g] + (d ? bhhB : bhhF)[g];
}

// ---------------------------------------------------------------------------
// xg chunk via MFMA, output now FRAGMENT-ORDERED for the scan:
// xgfrag[((ls*4 + b16)*64 + g16)*256 + lane*4 + r] = gate preact (fp16)
// where b = b16*16 + (lane>>4)*4 + r, g = g16*16 + (lane&15).
// ---------------------------------------------------------------------------
__global__ __launch_bounds__(256) void xg_mfma(
    int c, const int* __restrict__ embed, const float* __restrict__ emb,
    const __half* __restrict__ wihfrag, const float* __restrict__ biassum,
    __half* __restrict__ xgF, __half* __restrict__ xgB)
{
  const int d = blockIdx.z, ls = blockIdx.x, gblk = blockIdx.y;
  int t = c * CH + ls;
  if (d) t = TT - 1 - t;
  __half* xg = d ? xgB : xgF;
  const int tid = threadIdx.x, w = tid >> 6, l = tid & 63;

  __shared__ int idx[64];
  __shared__ unsigned short xs[64 * 256];   // 32 KB, swizzled fp16 x

  if (tid < 64) idx[tid] = embed[t * BB + tid];
  __syncthreads();

  // stage x: thread owns row rr, 64-col quarter cq
  {
    const int rr = tid >> 2, cq = (tid & 3) * 64;
    const float* src = emb + (size_t)idx[rr] * EE + cq;
#pragma unroll
    for (int j = 0; j < 8; ++j) {
      float4 a = *(const float4*)(src + j * 8);
      float4 b = *(const float4*)(src + j * 8 + 4);
      half8 hv;
      hv[0] = (_Float16)a.x; hv[1] = (_Float16)a.y; hv[2] = (_Float16)a.z; hv[3] = (_Float16)a.w;
      hv[4] = (_Float16)b.x; hv[5] = (_Float16)b.y; hv[6] = (_Float16)b.z; hv[7] = (_Float16)b.w;
      int hidx = (rr * 256 + cq + j * 8) ^ ((rr & 7) << 3);
      *(half8*)&xs[hidx] = hv;
    }
  }
  __syncthreads();

  // B fragments (L2-resident, frag-ordered)
  const __half* bfb = wihfrag + (size_t)((d * 64 + gblk * 4) * 8) * 512 + l * 8;
  half8 Bf[4][8];
#pragma unroll
  for (int ct = 0; ct < 4; ++ct)
#pragma unroll
    for (int ks = 0; ks < 8; ++ks)
      Bf[ct][ks] = *(const half8*)(bfb + (ct * 8 + ks) * 512);

  f32x4 acc[4];
#pragma unroll
  for (int ct = 0; ct < 4; ++ct) {
    float bv = biassum[d * 1024 + gblk * 64 + ct * 16 + (l & 15)];
    acc[ct][0] = bv; acc[ct][1] = bv; acc[ct][2] = bv; acc[ct][3] = bv;
  }

  const int arow = w * 16 + (l & 15);
#pragma unroll
  for (int ks = 0; ks < 8; ++ks) {
    int hidx = (arow * 256 + ks * 32 + (l >> 4) * 8) ^ ((arow & 7) << 3);
    half8 af = *(const half8*)&xs[hidx];
#pragma unroll
    for (int ct = 0; ct < 4; ++ct)
      acc[ct] = mfma16(af, Bf[ct][ks], acc[ct]);
  }

  // fragment-ordered store: b16 = w, g16 = gblk*4 + ct
#pragma unroll
  for (int ct = 0; ct < 4; ++ct) {
    ushort4 sv;
    sv.x = __half_as_ushort(__float2half(acc[ct][0]));
    sv.y = __half_as_ushort(__float2half(acc[ct][1]));
    sv.z = __half_as_ushort(__float2half(acc[ct][2]));
    sv.w = __half_as_ushort(__float2half(acc[ct][3]));
    size_t base = ((size_t)(ls * 4 + w) * 64 + (gblk * 4 + ct)) * 256 + l * 4;
    *(ushort4*)((unsigned short*)xg + base) = sv;
  }
}

// ---------------------------------------------------------------------------
// LSTM scan chunk via MFMA, hybrid weight residency.
// grid (4,2): 16 batch rows x dir. 512 threads = 8 waves, 2 waves/SIMD,
// __launch_bounds__(512,2) -> 256-VGPR budget.
// Wave w owns units [32w, 32w+32) x 4 gates = 64 1KB frags:
//   ks 0..3 -> VGPR (128 regs), ks 4..5 -> LDS (16KB/wave), ks 6..7 -> L2 stream.
// h fp16 in swizzled LDS double buffer; c f32 in regs.
// ---------------------------------------------------------------------------
__global__ __launch_bounds__(512, 2) void scan_mfma(
    int c, const __half* __restrict__ xgF, const __half* __restrict__ xgB,
    const __half* __restrict__ whhfrag,
    const float* __restrict__ hin, const float* __restrict__ cin,
    float* __restrict__ hstate, float* __restrict__ cstate,
    __half* __restrict__ outb)
{
  const int d = blockIdx.y, bx = blockIdx.x;
  const int tid = threadIdx.x, w = tid >> 6, l = tid & 63;
  const int m = l & 15, qr = l >> 4;
  const unsigned short* xg = (const unsigned short*)(d ? xgB : xgF);

  __shared__ unsigned short hb[2][16 * 256];            // 16 KB
  __shared__ unsigned short wlds[8][2][4][2][512];      // 128 KB [w][ut][q][ks-4][lane*8+r]

  // Per-(ut,q,ks) weight-frag address
#define WFRAG(ut, q, ks) \
  (whhfrag + ((size_t)((d * 16 + 2 * w + (ut)) * 32) + (q) * 8 + (ks)) * 512 + l * 8)

  // --- VGPR-resident frags: ks 0..3
  half8 Wf[2][4][4];
#pragma unroll
  for (int ut = 0; ut < 2; ++ut)
#pragma unroll
    for (int q = 0; q < 4; ++q)
#pragma unroll
      for (int ks = 0; ks < 4; ++ks)
        Wf[ut][q][ks] = *(const half8*)WFRAG(ut, q, ks);

  // --- LDS-resident frags: ks 4..5
#pragma unroll
  for (int ut = 0; ut < 2; ++ut)
#pragma unroll
    for (int q = 0; q < 4; ++q)
#pragma unroll
      for (int ks = 4; ks < 6; ++ks) {
        half8 v = *(const half8*)WFRAG(ut, q, ks);
        *(half8*)&wlds[w][ut][q][ks - 4][l * 8] = v;
      }

  // --- init h, c
  float cst[2][4];
#pragma unroll
  for (int ut = 0; ut < 2; ++ut)
#pragma unroll
    for (int r = 0; r < 4; ++r) {
      int br = qr * 4 + r;
      int gb = d * BB + bx * 16 + br;
      int u = 32 * w + 16 * ut + m;
      cst[ut][r] = cin[(size_t)gb * HH + u];
      hb[0][HSWZ(br, u)] = __half_as_ushort(__float2half(hin[(size_t)gb * HH + u]));
    }
  __syncthreads();

  int buf = 0;
  for (int ls = 0; ls < CH; ++ls) {
    int t = c * CH + ls;
    if (d) t = TT - 1 - t;

    // streamed frags ks6 (issue early; latency hidden by af/xg/MFMA ks0-3)
    half8 s[2][4];
#pragma unroll
    for (int ut = 0; ut < 2; ++ut)
#pragma unroll
      for (int q = 0; q < 4; ++q)
        s[ut][q] = *(const half8*)WFRAG(ut, q, 6);

    // A-frags: h_prev
    half8 af[8];
#pragma unroll
    for (int ks = 0; ks < 8; ++ks)
      af[ks] = *(const half8*)&hb[buf][HSWZ(m, ks * 32 + qr * 8) & ~7 | ((HSWZ(m, ks * 32 + qr * 8)) & 7)];

    // C-init from frag-ordered xg
    f32x4 acc[2][4];
#pragma unroll
    for (int ut = 0; ut < 2; ++ut)
#pragma unroll
      for (int q = 0; q < 4; ++q) {
        size_t base = ((size_t)(ls * 4 + bx) * 64 + (q * 16 + 2 * w + ut)) * 256 + l * 4;
        ushort4 sv = *(const ushort4*)(xg + base);
        acc[ut][q][0] = __half2float(__ushort_as_half(sv.x));
        acc[ut][q][1] = __half2float(__ushort_as_half(sv.y));
        acc[ut][q][2] = __half2float(__ushort_as_half(sv.z));
        acc[ut][q][3] = __half2float(__ushort_as_half(sv.w));
      }

    // MFMA ks0..3 (VGPR frags)
#pragma unroll
    for (int ks = 0; ks < 4; ++ks)
#pragma unroll
      for (int ut = 0; ut < 2; ++ut)
#pragma unroll
        for (int q = 0; q < 4; ++q)
          acc[ut][q] = mfma16(af[ks], Wf[ut][q][ks], acc[ut][q]);

    // MFMA ks6 (consume streamed s), then reuse s for ks7
#pragma unroll
    for (int ut = 0; ut < 2; ++ut)
#pragma unroll
      for (int q = 0; q < 4; ++q)
        acc[ut][q] = mfma16(af[6], s[ut][q], acc[ut][q]);

#pragma unroll
    for (int ut = 0; ut < 2; ++ut)
#pragma unroll
      for (int q = 0; q < 4; ++q)
        s[ut][q] = *(const half8*)WFRAG(ut, q, 7);

    // MFMA ks4..5 (LDS frags) — covers ks7 load latency
#pragma unroll
    for (int ks = 4; ks < 6; ++ks)
#pragma unroll
      for (int ut = 0; ut < 2; ++ut)
#pragma unroll
        for (int q = 0; q < 4; ++q) {
          half8 bf = *(const half8*)&wlds[w][ut][q][ks - 4][l * 8];
          acc[ut][q] = mfma16(af[ks], bf, acc[ut][q]);
        }

    // MFMA ks7
#pragma unroll
    for (int ut = 0; ut < 2; ++ut)
#pragma unroll
      for (int q = 0; q < 4; ++q)
        acc[ut][q] = mfma16(af[7], s[ut][q], acc[ut][q]);

    // epilogue: gates -> c,h ; write h to LDS + outb
#pragma unroll
    for (int ut = 0; ut < 2; ++ut)
#pragma unroll
      for (int r = 0; r < 4; ++r) {
        float ig = sigm(acc[ut][0][r]);
        float fg = sigm(acc[ut][1][r]);
        float gg = tanh_(acc[ut][2][r]);
        float og = sigm(acc[ut][3][r]);
        cst[ut][r] = fg * cst[ut][r] + ig * gg;
        float hv = og * tanh_(cst[ut][r]);
        int br = qr * 4 + r;
        int u = 32 * w + 16 * ut + m;
        unsigned short hu = __half_as_ushort(__float2half(hv));
        hb[buf ^ 1][HSWZ(br, u)] = hu;
        outb[((size_t)t * BB + bx * 16 + br) * DD + d * HH + u] = __ushort_as_half(hu);
      }
    __syncthreads();
    buf ^= 1;
  }

  // final states
#pragma unroll
  for (int ut = 0; ut < 2; ++ut)
#pragma unroll
    for (int r = 0; r < 4; ++r) {
      int br = qr * 4 + r;
      int gb = d * BB + bx * 16 + br;
      int u = 32 * w + 16 * ut + m;
      hstate[(size_t)gb * HH + u] = __half2float(__ushort_as_half(hb[buf][HSWZ(br, u)]));
      cstate[(size_t)gb * HH + u] = cst[ut][r];
    }
#undef WFRAG
}

// ---------------------------------------------------------------------------
// logits[r] = sum_e tanh( (out[r,:] @ W_word)[e] + b_word[e] ) * proj[e]
// ---------------------------------------------------------------------------
__global__ __launch_bounds__(1024, 1) void squish_logits(
    const __half* __restrict__ outb, const float* __restrict__ Ww,
    const float* __restrict__ bw, const float* __restrict__ proj,
    float* __restrict__ logits)
{
  const int r0 = blockIdx.x * 64;
  const int tid = threadIdx.x;
  const int tm = tid >> 6;        // 0..15
  const int tn = tid & 63;        // 0..63
  __shared__ float As[16][68];
  __shared__ float Bs[16][516];
  __shared__ float red[64][65];

  float acc[4][8] = {};
  const int am = tid >> 4, ak = tid & 15;
  const int bk = tid >> 7, bn = (tid & 127) * 4;

  for (int k0 = 0; k0 < DD; k0 += 16) {
    float a0 = __half2float(outb[(size_t)(r0 + am) * DD + k0 + ak]);
    float4 b0 = *(const float4*)&Ww[(size_t)(k0 + bk) * DD + bn];
    float4 b1 = *(const float4*)&Ww[(size_t)(k0 + bk + 8) * DD + bn];
    __syncthreads();
    As[ak][am] = a0;
    *(float4*)&Bs[bk][bn] = b0;
    *(float4*)&Bs[bk + 8][bn] = b1;
    __syncthreads();
#pragma unroll
    for (int k = 0; k < 16; ++k) {
      float4 a = *(const float4*)&As[k][tm * 4];
      float4 p0 = *(const float4*)&Bs[k][tn * 8];
      float4 p1 = *(const float4*)&Bs[k][tn * 8 + 4];
      float av[4] = {a.x, a.y, a.z, a.w};
#pragma unroll
      for (int i = 0; i < 4; ++i) {
        acc[i][0] += av[i] * p0.x; acc[i][1] += av[i] * p0.y;
        acc[i][2] += av[i] * p0.z; acc[i][3] += av[i] * p0.w;
        acc[i][4] += av[i] * p1.x; acc[i][5] += av[i] * p1.y;
        acc[i][6] += av[i] * p1.z; acc[i][7] += av[i] * p1.w;
      }
    }
  }
  float partial[4] = {0.f, 0.f, 0.f, 0.f};
#pragma unroll
  for (int jj = 0; jj < 8; ++jj) {
    int col = tn * 8 + jj;
    float bwv = bw[col], pv = proj[col];
#pragma unroll
    for (int i = 0; i < 4; ++i)
      partial[i] += tanhf(acc[i][jj] + bwv) * pv;
  }
#pragma unroll
  for (int i = 0; i < 4; ++i) red[tm * 4 + i][tn] = partial[i];
  __syncthreads();
  if (tid < 64) {
    float s = 0.f;
    for (int x = 0; x < 64; ++x) s += red[tid][x];
    logits[r0 + tid] = s;
  }
}

// ---------------------------------------------------------------------------
__global__ __launch_bounds__(256) void softmax_t(const float* __restrict__ logits,
                                                 float* __restrict__ attn)
{
  const int b = blockIdx.x;
  const int tid = threadIdx.x;
  __shared__ float sm[256];
  float v0 = logits[tid * BB + b];
  float v1 = logits[(tid + 256) * BB + b];
  sm[tid] = fmaxf(v0, v1);
  __syncthreads();
  for (int s = 128; s > 0; s >>= 1) {
    if (tid < s) sm[tid] = fmaxf(sm[tid], sm[tid + s]);
    __syncthreads();
  }
  float M = sm[0];
  __syncthreads();
  float e0 = expf(v0 - M), e1 = expf(v1 - M);
  sm[tid] = e0 + e1;
  __syncthreads();
  for (int s = 128; s > 0; s >>= 1) {
    if (tid < s) sm[tid] += sm[tid + s];
    __syncthreads();
  }
  float inv = 1.f / sm[0];
  attn[tid * BB + b] = e0 * inv;
  attn[(tid + 256) * BB + b] = e1 * inv;
}

// ---------------------------------------------------------------------------
__global__ __launch_bounds__(512) void vec_final(
    const __half* __restrict__ outb, const float* __restrict__ attn,
    const float* __restrict__ linW, const float* __restrict__ linb,
    float* __restrict__ y)
{
  const int b = blockIdx.x;
  const int d = threadIdx.x;
  float acc = 0.f;
  for (int t = 0; t < TT; ++t)
    acc += attn[t * BB + b] * __half2float(outb[((size_t)t * BB + b) * DD + d]);
  __shared__ float red[512];
  for (int cls = 0; cls < NCLS; ++cls) {
    red[d] = acc * linW[cls * DD + d];
    __syncthreads();
    for (int s = 256; s > 0; s >>= 1) {
      if (d < s) red[d] += red[d + s];
      __syncthreads();
    }
    if (d == 0) y[b * NCLS + cls] = red[0] + linb[cls];
    __syncthreads();
  }
}

// ---------------------------------------------------------------------------
extern "C" void kernel_launch(void* const* d_in, const int* in_sizes, int n_in,
                              void* d_out, int out_size, void* d_ws, size_t ws_size,
                              hipStream_t stream) {
  const int*   embed     = (const int*)d_in[0];
  const float* h0        = (const float*)d_in[1];
  const float* c0        = (const float*)d_in[2];
  const float* emb_table = (const float*)d_in[3];
  const float* Wih_f     = (const float*)d_in[4];
  const float* Whh_f     = (const float*)d_in[5];
  const float* bih_f     = (const float*)d_in[6];
  const float* bhh_f     = (const float*)d_in[7];
  const float* Wih_b     = (const float*)d_in[8];
  const float* Whh_b     = (const float*)d_in[9];
  const float* bih_b     = (const float*)d_in[10];
  const float* bhh_b     = (const float*)d_in[11];
  const float* W_word    = (const float*)d_in[12];
  const float* b_word    = (const float*)d_in[13];
  const float* proj_word = (const float*)d_in[14];
  const float* lin_W     = (const float*)d_in[15];
  const float* lin_b     = (const float*)d_in[16];

  char* ws = (char*)d_ws;
  __half* xgF     = (__half*)(ws + OFF_XGF);
  __half* xgB     = (__half*)(ws + OFF_XGB);
  __half* outb    = (__half*)(ws + OFF_OUTB);
  __half* whhfrag = (__half*)(ws + OFF_WHHF);
  __half* wihfrag = (__half*)(ws + OFF_WIHF);
  float*  biassum = (float*)(ws + OFF_BIAS);
  float*  hstate  = (float*)(ws + OFF_HST);
  float*  cstate  = (float*)(ws + OFF_CST);
  float*  logits  = (float*)(ws + OFF_LOG);
  float*  attn    = (float*)(ws + OFF_ATT);

  make_frags<<<4096, 256, 0, stream>>>(Whh_f, Whh_b, Wih_f, Wih_b, whhfrag, wihfrag);
  bias_prep<<<8, 256, 0, stream>>>(bih_f, bhh_f, bih_b, bhh_b, biassum);

  for (int c = 0; c < NCH; ++c) {
    xg_mfma<<<dim3(CH, 16, 2), 256, 0, stream>>>(c, embed, emb_table,
        wihfrag, biassum, xgF, xgB);
    const float* hin = (c == 0) ? h0 : hstate;
    const float* cin = (c == 0) ? c0 : cstate;
    scan_mfma<<<dim3(4, 2), 512, 0, stream>>>(c, xgF, xgB, whhfrag,
        hin, cin, hstate, cstate, outb);
  }

  squish_logits<<<512, 1024, 0, stream>>>(outb, W_word, b_word, proj_word, logits);
  softmax_t<<<64, 256, 0, stream>>>(logits, attn);
  vec_final<<<64, 512, 0, stream>>>(outb, attn, lin_W, lin_b, (float*)d_out);
}

// Round 6
// 3177.047 us; speedup vs baseline: 1.5599x; 1.1856x over previous
//
#include <hip/hip_runtime.h>
#include <hip/hip_fp16.h>
#include <cstdint>
#include <cstddef>

#define TT 512
#define BB 64
#define EE 256
#define HH 256
#define G4 1024   // 4*H
#define DD 512    // 2*H
#define NCLS 5
#define CH 64     // time-steps per chunk
#define NCH (TT / CH)

typedef _Float16 half8 __attribute__((ext_vector_type(8)));
typedef float f32x4 __attribute__((ext_vector_type(4)));

// Workspace layout (bytes). Total = 53,157,888 B (~50.7 MB).
#define OFF_XGF   0ull                 // 8,388,608  fp16 frag-ordered [CH*4][64][256]
#define OFF_XGB   8388608ull           // 8,388,608
#define OFF_OUTB  16777216ull          // 33,554,432 fp16 [512][64][512]
#define OFF_WHHF  50331648ull          // 1,048,576  fp16 frag [2][64 pf][8 ks][64 lane][8 r]
#define OFF_WIHF  51380224ull          // 1,048,576  fp16 frag [2][64 pf][8 ks][64 lane][8 r]
#define OFF_BIAS  52428800ull          // 8,192      f32 [2][1024]  (pcol-permuted)
#define OFF_HST   52436992ull          // 131,072    f32 [2][64][256]
#define OFF_CST   52568064ull          // 131,072
#define OFF_LOG   52699136ull          // 131,072    f32 [512][64]
#define OFF_ATT   52830208ull          // 131,072
#define OFF_HEX   52961280ull          // 131,072    fp16 [2 dir][2 parity][64 row][256 unit]
#define OFF_FLG   53092352ull          // 65,536     int  [2][8 c][64 ls][4 bg][4 ug]

__device__ __forceinline__ f32x4 mfma16(half8 a, half8 b, f32x4 c) {
  return __builtin_amdgcn_mfma_f32_16x16x32_f16(a, b, c, 0, 0, 0);
}
__device__ __forceinline__ float sigm(float x) {
  return __fdividef(1.f, 1.f + __expf(-x));
}
__device__ __forceinline__ float tanh_(float x) {
  float e = __expf(2.f * x);
  return 1.f - __fdividef(2.f, e + 1.f);
}
__device__ __forceinline__ f32x4 shflx4(f32x4 v, int mask) {
  f32x4 r;
  r[0] = __shfl_xor(v[0], mask, 64);
  r[1] = __shfl_xor(v[1], mask, 64);
  r[2] = __shfl_xor(v[2], mask, 64);
  r[3] = __shfl_xor(v[3], mask, 64);
  return r;
}

// h LDS swizzle: row br, unit u -> ushort index (XOR on bits 3..5 keeps 8-elem
// vectors contiguous; spreads the 16 A-rows across bank quads)
#define HSWZ(br, u) ((((br) * 256) + (u)) ^ (((br) & 7) << 3))

// ---------------------------------------------------------------------------
// Fragment-order the weights (fp16), GATE-PERMUTED columns:
//   pcol = unit*4 + gate  ->  pf = pcol>>4, m = pcol&15
//   frag[d][pf][ks][lane][r] = W_d[g][k],  g = (m&3)*256 + pf*4 + (m>>2),
//   k = ks*32 + (lane>>4)*8 + r,  m = lane&15.
// This puts the 4 gates of one unit in 4 ADJACENT lanes of the MFMA output.
// ---------------------------------------------------------------------------
__global__ __launch_bounds__(256) void make_frags(
    const float* __restrict__ WhhF, const float* __restrict__ WhhB,
    const float* __restrict__ WihF, const float* __restrict__ WihB,
    __half* __restrict__ whhfrag, __half* __restrict__ wihfrag)
{
  int idx = blockIdx.x * 256 + threadIdx.x;   // 0 .. 2^20-1
  int r = idx & 7, lane = (idx >> 3) & 63, ks = (idx >> 9) & 7;
  int mm = lane & 15;
  int k = ks * 32 + (lane >> 4) * 8 + r;
  if (idx < (1 << 19)) {
    int pf = (idx >> 12) & 63, d = (idx >> 18) & 1;
    const float* W = d ? WhhB : WhhF;
    int g = (mm & 3) * 256 + pf * 4 + (mm >> 2);
    whhfrag[idx] = __float2half(W[(size_t)g * HH + k]);
  } else {
    int e = idx - (1 << 19);
    int pf = (e >> 12) & 63, d = (e >> 18) & 1;
    const float* W = d ? WihB : WihF;
    int g = (mm & 3) * 256 + pf * 4 + (mm >> 2);
    wihfrag[e] = __float2half(W[(size_t)g * EE + k]);
  }
}

__global__ __launch_bounds__(256) void bias_prep(
    const float* __restrict__ bihF, const float* __restrict__ bhhF,
    const float* __restrict__ bihB, const float* __restrict__ bhhB,
    float* __restrict__ bias)
{
  int i = blockIdx.x * 256 + threadIdx.x;    // 0..2047
  int d = i >> 10, pcol = i & 1023;
  int g = (pcol & 3) * 256 + (pcol >> 2);
  bias[i] = (d ? bihB : bihF)[g] + (d ? bhhB : bhhF)[g];
}

// ---------------------------------------------------------------------------
// xg chunk via MFMA, output fragment-ordered (pcol frags) for the scan:
// xgfrag[((ls*4 + b16)*64 + pf)*256 + lane*4 + r]  (fp16)
// ---------------------------------------------------------------------------
__global__ __launch_bounds__(256) void xg_mfma(
    int c, const int* __restrict__ embed, const float* __restrict__ emb,
    const __half* __restrict__ wihfrag, const float* __restrict__ biassum,
    __half* __restrict__ xgF, __half* __restrict__ xgB)
{
  const int d = blockIdx.z, ls = blockIdx.x, gblk = blockIdx.y;
  int t = c * CH + ls;
  if (d) t = TT - 1 - t;
  __half* xg = d ? xgB : xgF;
  const int tid = threadIdx.x, w = tid >> 6, l = tid & 63;

  __shared__ int idx[64];
  __shared__ unsigned short xs[64 * 256];   // 32 KB, swizzled fp16 x

  if (tid < 64) idx[tid] = embed[t * BB + tid];
  __syncthreads();

  {
    const int rr = tid >> 2, cq = (tid & 3) * 64;
    const float* src = emb + (size_t)idx[rr] * EE + cq;
#pragma unroll
    for (int j = 0; j < 8; ++j) {
      float4 a = *(const float4*)(src + j * 8);
      float4 b = *(const float4*)(src + j * 8 + 4);
      half8 hv;
      hv[0] = (_Float16)a.x; hv[1] = (_Float16)a.y; hv[2] = (_Float16)a.z; hv[3] = (_Float16)a.w;
      hv[4] = (_Float16)b.x; hv[5] = (_Float16)b.y; hv[6] = (_Float16)b.z; hv[7] = (_Float16)b.w;
      int hidx = (rr * 256 + cq + j * 8) ^ ((rr & 7) << 3);
      *(half8*)&xs[hidx] = hv;
    }
  }
  __syncthreads();

  const __half* bfb = wihfrag + (size_t)((d * 64 + gblk * 4) * 8) * 512 + l * 8;
  half8 Bf[4][8];
#pragma unroll
  for (int ct = 0; ct < 4; ++ct)
#pragma unroll
    for (int ks = 0; ks < 8; ++ks)
      Bf[ct][ks] = *(const half8*)(bfb + (ct * 8 + ks) * 512);

  f32x4 acc[4];
#pragma unroll
  for (int ct = 0; ct < 4; ++ct) {
    float bv = biassum[d * 1024 + gblk * 64 + ct * 16 + (l & 15)];
    acc[ct][0] = bv; acc[ct][1] = bv; acc[ct][2] = bv; acc[ct][3] = bv;
  }

  const int arow = w * 16 + (l & 15);
#pragma unroll
  for (int ks = 0; ks < 8; ++ks) {
    int hidx = (arow * 256 + ks * 32 + (l >> 4) * 8) ^ ((arow & 7) << 3);
    half8 af = *(const half8*)&xs[hidx];
#pragma unroll
    for (int ct = 0; ct < 4; ++ct)
      acc[ct] = mfma16(af, Bf[ct][ks], acc[ct]);
  }

#pragma unroll
  for (int ct = 0; ct < 4; ++ct) {
    ushort4 sv;
    sv.x = __half_as_ushort(__float2half(acc[ct][0]));
    sv.y = __half_as_ushort(__float2half(acc[ct][1]));
    sv.z = __half_as_ushort(__float2half(acc[ct][2]));
    sv.w = __half_as_ushort(__float2half(acc[ct][3]));
    size_t base = ((size_t)(ls * 4 + w) * 64 + (gblk * 4 + ct)) * 256 + l * 4;
    *(ushort4*)((unsigned short*)xg + base) = sv;
  }
}

// ---------------------------------------------------------------------------
// Distributed persistent LSTM scan. grid (16,2): x = bg*4+ug, y = dir.
// Block: 512 thr (8 waves), owns 16 batch rows (bg) x 64 units (ug).
// Weights fully VGPR-resident (64 VGPR/lane). Per step: MFMA from LDS-h,
// gate butterfly via shfl_xor, publish h-slice to global hex (parity dbuf) +
// agent-scope release flag; acquire 3 peer flags, stage peer slices to LDS.
// ---------------------------------------------------------------------------
__global__ __launch_bounds__(512, 2) void scan_dist(
    int c, const __half* __restrict__ xgF, const __half* __restrict__ xgB,
    const __half* __restrict__ whhfrag,
    const float* __restrict__ hin, const float* __restrict__ cin,
    float* __restrict__ hstate, float* __restrict__ cstate,
    __half* __restrict__ outb, __half* __restrict__ hex, int* __restrict__ flags)
{
  const int d = blockIdx.y;
  const int bg = blockIdx.x >> 2, ug = blockIdx.x & 3;
  const int tid = threadIdx.x, w = tid >> 6, l = tid & 63;
  const int m = l & 15, qr = l >> 4, q = m & 3, ul = m >> 2;
  const unsigned short* xg = (const unsigned short*)(d ? xgB : xgF);

  __shared__ unsigned short hb[16 * 256];   // 8 KB: 16 rows x 256 units fp16

  const int pf0 = ug * 16 + w * 2;          // wave owns pcol-frags pf0, pf0+1

  // B fragments, VGPR-resident for the whole chunk (2 x 8 x 4 VGPR = 64)
  half8 Wf[2][8];
#pragma unroll
  for (int cf = 0; cf < 2; ++cf)
#pragma unroll
    for (int ks = 0; ks < 8; ++ks)
      Wf[cf][ks] = *(const half8*)(whhfrag +
          ((size_t)(d * 64 + pf0 + cf) * 8 + ks) * 512 + l * 8);

  // stage h_in (16 rows x 256 units) and c_in (own units)
#pragma unroll
  for (int i = 0; i < 8; ++i) {
    int idx = i * 512 + tid;
    int r = idx >> 8, u = idx & 255;
    hb[HSWZ(r, u)] = __half_as_ushort(
        __float2half(hin[(size_t)(d * BB + bg * 16 + r) * HH + u]));
  }
  float cst[2][4];
#pragma unroll
  for (int cf = 0; cf < 2; ++cf) {
    int U = (pf0 + cf) * 4 + ul;
#pragma unroll
    for (int j = 0; j < 4; ++j)
      cst[cf][j] = cin[(size_t)(d * BB + bg * 16 + qr * 4 + j) * HH + U];
  }
  __syncthreads();

  for (int ls = 0; ls < CH; ++ls) {
    int t = c * CH + ls;
    if (d) t = TT - 1 - t;

    // C-init loads (global, independent of hb) issued first
    ushort4 xv[2];
#pragma unroll
    for (int cf = 0; cf < 2; ++cf) {
      size_t base = ((size_t)(ls * 4 + bg) * 64 + (pf0 + cf)) * 256 + l * 4;
      xv[cf] = *(const ushort4*)(xg + base);
    }
    // A-frags: h_prev from LDS
    half8 af[8];
#pragma unroll
    for (int ks = 0; ks < 8; ++ks)
      af[ks] = *(const half8*)&hb[HSWZ(m, ks * 32 + qr * 8)];
    __syncthreads();   // af in regs; hb free for this step's h writes

    f32x4 acc[2];
#pragma unroll
    for (int cf = 0; cf < 2; ++cf) {
      acc[cf][0] = __half2float(__ushort_as_half(xv[cf].x));
      acc[cf][1] = __half2float(__ushort_as_half(xv[cf].y));
      acc[cf][2] = __half2float(__ushort_as_half(xv[cf].z));
      acc[cf][3] = __half2float(__ushort_as_half(xv[cf].w));
    }
#pragma unroll
    for (int ks = 0; ks < 8; ++ks)
#pragma unroll
      for (int cf = 0; cf < 2; ++cf)
        acc[cf] = mfma16(af[ks], Wf[cf][ks], acc[cf]);

    // epilogue: gate butterfly (lanes 4u..4u+3 hold i,f,g,o of unit u)
    __half* hslice = hex + (size_t)(d * 2 + (ls & 1)) * 64 * 256;
#pragma unroll
    for (int cf = 0; cf < 2; ++cf) {
      f32x4 e = acc[cf];
      f32x4 o1 = shflx4(e, 1);
      f32x4 gev = (q & 1) ? o1 : e;    // gate q&~1
      f32x4 gov = (q & 1) ? e : o1;    // gate q|1
      f32x4 ge2 = shflx4(gev, 2);
      f32x4 go2 = shflx4(gov, 2);
      f32x4 gi = (q & 2) ? ge2 : gev;  // gate 0 (i)
      f32x4 gg = (q & 2) ? gev : ge2;  // gate 2 (g)
      f32x4 gf = (q & 2) ? go2 : gov;  // gate 1 (f)
      f32x4 go = (q & 2) ? gov : go2;  // gate 3 (o)
      int U = (pf0 + cf) * 4 + ul;
#pragma unroll
      for (int j = 0; j < 4; ++j) {
        float ig = sigm(gi[j]), fg = sigm(gf[j]);
        float gz = tanh_(gg[j]), og = sigm(go[j]);
        cst[cf][j] = fg * cst[cf][j] + ig * gz;
        float hv = og * tanh_(cst[cf][j]);
        if (q == 0) {
          int r = qr * 4 + j;
          unsigned short hu = __half_as_ushort(__float2half(hv));
          hb[HSWZ(r, U)] = hu;
          hslice[(size_t)(bg * 16 + r) * 256 + U] = __ushort_as_half(hu);
          outb[((size_t)t * BB + bg * 16 + r) * DD + d * HH + U] = __ushort_as_half(hu);
        }
      }
    }
    __syncthreads();   // all hex/outb stores drained (vmcnt 0 at barrier)

    const int fbase = (((d * NCH + c) * CH + ls) * 4 + bg) * 4;
    if (tid == 0)
      __hip_atomic_store(&flags[fbase + ug], 1, __ATOMIC_RELEASE,
                         __HIP_MEMORY_SCOPE_AGENT);
    if (tid < 4 && tid != ug) {
      while (__hip_atomic_load(&flags[fbase + tid], __ATOMIC_ACQUIRE,
                               __HIP_MEMORY_SCOPE_AGENT) == 0)
        __builtin_amdgcn_s_sleep(4);
    }
    __syncthreads();

    // stage the 3 peer slices (16 rows x 64 units each) into hb
    {
      const unsigned short* hsrc =
          (const unsigned short*)hex + (size_t)(d * 2 + (ls & 1)) * 64 * 256;
      int r = tid >> 5, u2 = (tid & 31) * 2;
#pragma unroll
      for (int p = 0; p < 3; ++p) {
        int peer = p + (p >= ug ? 1 : 0);
        int u = peer * 64 + u2;
        const unsigned short* s2 = hsrc + (size_t)(bg * 16 + r) * 256 + u;
        int hi = HSWZ(r, u);
        hb[hi] = s2[0];
        hb[hi + 1] = s2[1];
      }
    }
    __syncthreads();   // hb complete for next step
  }

  // final states
#pragma unroll
  for (int i = 0; i < 8; ++i) {
    int idx = i * 512 + tid;
    int r = idx >> 8, u = idx & 255;
    hstate[(size_t)(d * BB + bg * 16 + r) * HH + u] =
        __half2float(__ushort_as_half(hb[HSWZ(r, u)]));
  }
  if (q == 0) {
#pragma unroll
    for (int cf = 0; cf < 2; ++cf) {
      int U = (pf0 + cf) * 4 + ul;
#pragma unroll
      for (int j = 0; j < 4; ++j)
        cstate[(size_t)(d * BB + bg * 16 + qr * 4 + j) * HH + U] = cst[cf][j];
    }
  }
}

// ---------------------------------------------------------------------------
// logits[r] = sum_e tanh( (out[r,:] @ W_word)[e] + b_word[e] ) * proj[e]
// ---------------------------------------------------------------------------
__global__ __launch_bounds__(1024, 1) void squish_logits(
    const __half* __restrict__ outb, const float* __restrict__ Ww,
    const float* __restrict__ bw, const float* __restrict__ proj,
    float* __restrict__ logits)
{
  const int r0 = blockIdx.x * 64;
  const int tid = threadIdx.x;
  const int tm = tid >> 6;        // 0..15
  const int tn = tid & 63;        // 0..63
  __shared__ float As[16][68];
  __shared__ float Bs[16][516];
  __shared__ float red[64][65];

  float acc[4][8] = {};
  const int am = tid >> 4, ak = tid & 15;
  const int bk = tid >> 7, bn = (tid & 127) * 4;

  for (int k0 = 0; k0 < DD; k0 += 16) {
    float a0 = __half2float(outb[(size_t)(r0 + am) * DD + k0 + ak]);
    float4 b0 = *(const float4*)&Ww[(size_t)(k0 + bk) * DD + bn];
    float4 b1 = *(const float4*)&Ww[(size_t)(k0 + bk + 8) * DD + bn];
    __syncthreads();
    As[ak][am] = a0;
    *(float4*)&Bs[bk][bn] = b0;
    *(float4*)&Bs[bk + 8][bn] = b1;
    __syncthreads();
#pragma unroll
    for (int k = 0; k < 16; ++k) {
      float4 a = *(const float4*)&As[k][tm * 4];
      float4 p0 = *(const float4*)&Bs[k][tn * 8];
      float4 p1 = *(const float4*)&Bs[k][tn * 8 + 4];
      float av[4] = {a.x, a.y, a.z, a.w};
#pragma unroll
      for (int i = 0; i < 4; ++i) {
        acc[i][0] += av[i] * p0.x; acc[i][1] += av[i] * p0.y;
        acc[i][2] += av[i] * p0.z; acc[i][3] += av[i] * p0.w;
        acc[i][4] += av[i] * p1.x; acc[i][5] += av[i] * p1.y;
        acc[i][6] += av[i] * p1.z; acc[i][7] += av[i] * p1.w;
      }
    }
  }
  float partial[4] = {0.f, 0.f, 0.f, 0.f};
#pragma unroll
  for (int jj = 0; jj < 8; ++jj) {
    int col = tn * 8 + jj;
    float bwv = bw[col], pv = proj[col];
#pragma unroll
    for (int i = 0; i < 4; ++i)
      partial[i] += tanhf(acc[i][jj] + bwv) * pv;
  }
#pragma unroll
  for (int i = 0; i < 4; ++i) red[tm * 4 + i][tn] = partial[i];
  __syncthreads();
  if (tid < 64) {
    float s = 0.f;
    for (int x = 0; x < 64; ++x) s += red[tid][x];
    logits[r0 + tid] = s;
  }
}

// ---------------------------------------------------------------------------
__global__ __launch_bounds__(256) void softmax_t(const float* __restrict__ logits,
                                                 float* __restrict__ attn)
{
  const int b = blockIdx.x;
  const int tid = threadIdx.x;
  __shared__ float sm[256];
  float v0 = logits[tid * BB + b];
  float v1 = logits[(tid + 256) * BB + b];
  sm[tid] = fmaxf(v0, v1);
  __syncthreads();
  for (int s = 128; s > 0; s >>= 1) {
    if (tid < s) sm[tid] = fmaxf(sm[tid], sm[tid + s]);
    __syncthreads();
  }
  float M = sm[0];
  __syncthreads();
  float e0 = expf(v0 - M), e1 = expf(v1 - M);
  sm[tid] = e0 + e1;
  __syncthreads();
  for (int s = 128; s > 0; s >>= 1) {
    if (tid < s) sm[tid] += sm[tid + s];
    __syncthreads();
  }
  float inv = 1.f / sm[0];
  attn[tid * BB + b] = e0 * inv;
  attn[(tid + 256) * BB + b] = e1 * inv;
}

// ---------------------------------------------------------------------------
__global__ __launch_bounds__(512) void vec_final(
    const __half* __restrict__ outb, const float* __restrict__ attn,
    const float* __restrict__ linW, const float* __restrict__ linb,
    float* __restrict__ y)
{
  const int b = blockIdx.x;
  const int d = threadIdx.x;
  float acc = 0.f;
  for (int t = 0; t < TT; ++t)
    acc += attn[t * BB + b] * __half2float(outb[((size_t)t * BB + b) * DD + d]);
  __shared__ float red[512];
  for (int cls = 0; cls < NCLS; ++cls) {
    red[d] = acc * linW[cls * DD + d];
    __syncthreads();
    for (int s = 256; s > 0; s >>= 1) {
      if (d < s) red[d] += red[d + s];
      __syncthreads();
    }
    if (d == 0) y[b * NCLS + cls] = red[0] + linb[cls];
    __syncthreads();
  }
}

// ---------------------------------------------------------------------------
extern "C" void kernel_launch(void* const* d_in, const int* in_sizes, int n_in,
                              void* d_out, int out_size, void* d_ws, size_t ws_size,
                              hipStream_t stream) {
  const int*   embed     = (const int*)d_in[0];
  const float* h0        = (const float*)d_in[1];
  const float* c0        = (const float*)d_in[2];
  const float* emb_table = (const float*)d_in[3];
  const float* Wih_f     = (const float*)d_in[4];
  const float* Whh_f     = (const float*)d_in[5];
  const float* bih_f     = (const float*)d_in[6];
  const float* bhh_f     = (const float*)d_in[7];
  const float* Wih_b     = (const float*)d_in[8];
  const float* Whh_b     = (const float*)d_in[9];
  const float* bih_b     = (const float*)d_in[10];
  const float* bhh_b     = (const float*)d_in[11];
  const float* W_word    = (const float*)d_in[12];
  const float* b_word    = (const float*)d_in[13];
  const float* proj_word = (const float*)d_in[14];
  const float* lin_W     = (const float*)d_in[15];
  const float* lin_b     = (const float*)d_in[16];

  char* ws = (char*)d_ws;
  __half* xgF     = (__half*)(ws + OFF_XGF);
  __half* xgB     = (__half*)(ws + OFF_XGB);
  __half* outb    = (__half*)(ws + OFF_OUTB);
  __half* whhfrag = (__half*)(ws + OFF_WHHF);
  __half* wihfrag = (__half*)(ws + OFF_WIHF);
  float*  biassum = (float*)(ws + OFF_BIAS);
  float*  hstate  = (float*)(ws + OFF_HST);
  float*  cstate  = (float*)(ws + OFF_CST);
  float*  logits  = (float*)(ws + OFF_LOG);
  float*  attn    = (float*)(ws + OFF_ATT);
  __half* hex     = (__half*)(ws + OFF_HEX);
  int*    flags   = (int*)(ws + OFF_FLG);

  // zero the exchange flags every launch (deterministic; graph-capturable)
  hipMemsetAsync(flags, 0, 65536, stream);

  make_frags<<<4096, 256, 0, stream>>>(Whh_f, Whh_b, Wih_f, Wih_b, whhfrag, wihfrag);
  bias_prep<<<8, 256, 0, stream>>>(bih_f, bhh_f, bih_b, bhh_b, biassum);

  for (int c = 0; c < NCH; ++c) {
    xg_mfma<<<dim3(CH, 16, 2), 256, 0, stream>>>(c, embed, emb_table,
        wihfrag, biassum, xgF, xgB);
    const float* hin = (c == 0) ? h0 : hstate;
    const float* cin = (c == 0) ? c0 : cstate;
    scan_dist<<<dim3(16, 2), 512, 0, stream>>>(c, xgF, xgB, whhfrag,
        hin, cin, hstate, cstate, outb, hex, flags);
  }

  squish_logits<<<512, 1024, 0, stream>>>(outb, W_word, b_word, proj_word, logits);
  softmax_t<<<64, 256, 0, stream>>>(logits, attn);
  vec_final<<<64, 512, 0, stream>>>(outb, attn, lin_W, lin_b, (float*)d_out);
}